// Round 7
// baseline (102.539 us; speedup 1.0000x reference)
//
#include <hip/hip_runtime.h>

#define GAMMA 0.99f
constexpr int T_DIM = 128;
constexpr int B_DIM = 512;
constexpr int Q_DIM = 50;
constexpr int NROW  = (T_DIM - 1) * B_DIM;   // 65024 loss rows (t<127)
constexpr int SLOT  = 52;                    // LDS ret row stride (208B, 16B-aligned)
constexpr int PACC  = 26;                    // LDS partial row stride
constexpr int R_BLK = 20;                    // ret rows per block
constexpr int KEEP  = -1;
constexpr int GRID_LOSS = (NROW + R_BLK - 1) / R_BLK;   // 3252

// ---------------------------------------------------------------------------
// K1: parallel segmented suffix scan of affine maps, one block per b.
// ret[t,b,q] = alpha*tv[anchor,b,q] + beta.  Hillis-Steele over 128 t's:
// 7 LDS rounds, no serial memory chains.  Coeff layout [b][128].
// Thread 127 also writes the required zero at out[127*B+b] (no memset node).
// ---------------------------------------------------------------------------
__global__ void __launch_bounds__(128) coeff_kernel(
    const float* __restrict__ reward,
    const int*   __restrict__ step_type,
    const float* __restrict__ discount,
    float* __restrict__ alpha,
    float* __restrict__ beta,
    int*   __restrict__ anchor,
    float* __restrict__ out) {
  __shared__ float sp[128], sqa[128], sqb[128];
  __shared__ int   snv[128];
  const int t = threadIdx.x;
  const int b = blockIdx.x;

  float p, qa, qb; int nv;
  if (t < T_DIM - 1) {
    const bool  last = (step_type[t * B_DIM + b] == 2);
    const float d    = GAMMA * discount[(t + 1) * B_DIM + b];
    const float r    = reward[(t + 1) * B_DIM + b];
    p  = last ? 0.0f : d;
    qa = last ? 1.0f : 0.0f;
    qb = last ? 0.0f : r;
    nv = last ? t    : KEEP;
  } else {                       // t = 127: identity element
    p = 1.0f; qa = 0.0f; qb = 0.0f; nv = KEEP;
    out[(T_DIM - 1) * B_DIM + b] = 0.0f;     // zero row of the output
  }
  sp[t] = p; sqa[t] = qa; sqb[t] = qb; snv[t] = nv;
  __syncthreads();

#pragma unroll
  for (int off = 1; off < 128; off <<= 1) {
    const bool act = (t + off) < 128;
    float p2 = 1.0f, qa2 = 0.0f, qb2 = 0.0f; int nv2 = KEEP;
    if (act) { p2 = sp[t+off]; qa2 = sqa[t+off]; qb2 = sqb[t+off]; nv2 = snv[t+off]; }
    __syncthreads();
    if (act) {
      qa = fmaf(p, qa2, qa);     // self is the OUTER map (applied last)
      qb = fmaf(p, qb2, qb);
      p  = p * p2;
      nv = (nv == KEEP) ? nv2 : nv;
      sp[t] = p; sqa[t] = qa; sqb[t] = qb; snv[t] = nv;
    }
    __syncthreads();
  }

  if (t < T_DIM - 1) {
    const int row = (b << 7) + t;            // [b][128] layout
    alpha[row]  = p + qa;                    // applied to a-init = 1
    beta[row]   = qb;                        // applied to be-init = 0
    anchor[row] = (nv == KEEP) ? (T_DIM - 1) : nv;
  }
}

// ---------------------------------------------------------------------------
// K2: quantile huber loss.  Block = 256 threads; thread owns TWO quantiles
// (j = jh, jh+25) of one row => each ds_read_b128 of ret feeds 8 pairs,
// halving LDS-pipe demand (which had become the binding pipe).
// 25 threads/row, 10 rows/pass, 2 passes over R_BLK=20 staged rows.
// 5-op pair math (verified identity):
//   d = ret_i - v; c = med3(d,-1,1); e = d - 0.5c
//   huber = e*c;  sgn(d)*huber = e*|c|
//   sum w*h = 0.5*sum(e*c) + (tau-0.5)*sum(e*|c|)
// ---------------------------------------------------------------------------
__global__ void __launch_bounds__(256) loss_kernel(
    const float* __restrict__ value,
    const float* __restrict__ tv,
    const float* __restrict__ alpha,
    const float* __restrict__ beta,
    const int*   __restrict__ anchor,
    float*       __restrict__ out) {
  __shared__ __align__(16) float sret[R_BLK * SLOT];
  __shared__ float pacc[R_BLK * PACC];

  const int tid = threadIdx.x;
  const int r0  = blockIdx.x * R_BLK;

  // ---- stage ret rows r0..r0+19 into LDS (4 passes of 256 threads) ----
  for (int e = tid; e < R_BLK * Q_DIM; e += 256) {
    const int lr  = e / Q_DIM;
    const int i   = e - lr * Q_DIM;
    const int row = r0 + lr;
    float rv = 0.0f;
    if (row < NROW) {
      const int b  = row & (B_DIM - 1);
      const int t  = row >> 9;
      const int ci = (b << 7) + t;          // coeff [b][128] layout
      const int n  = anchor[ci];
      rv = fmaf(alpha[ci], tv[(n * B_DIM + b) * Q_DIM + i], beta[ci]);
    }
    sret[lr * SLOT + i] = rv;
  }
  __syncthreads();

  const bool act   = tid < 250;
  const int  r_off = tid / 25;              // 0..9
  const int  jh    = tid - r_off * 25;      // 0..24
  const float ta   = ((float)jh + 0.5f) * (1.0f / Q_DIM) - 0.5f;   // tau_j - .5
  const float tb   = ta + 0.5f;                                    // tau_{j+25}-.5

  if (act) {
    // hoisted value loads (rows r0+r_off and r0+10+r_off always < 65536)
    const int row0 = r0 + r_off;
    const int row1 = row0 + 10;
    const float va0 = value[row0 * Q_DIM + jh];
    const float vb0 = value[row0 * Q_DIM + jh + 25];
    const float va1 = value[row1 * Q_DIM + jh];
    const float vb1 = value[row1 * Q_DIM + jh + 25];

#pragma unroll
    for (int rb = 0; rb < 2; ++rb) {
      const int lr = rb * 10 + r_off;       // 0..19
      const float* rp = &sret[lr * SLOT];
      const float va = rb ? va1 : va0;
      const float vb = rb ? vb1 : vb0;

      float s1a = 0.0f, s2a = 0.0f, s1b = 0.0f, s2b = 0.0f;
      auto pair = [&](float reti) {
        const float da = reti - va;
        const float ca = __builtin_amdgcn_fmed3f(da, -1.0f, 1.0f);
        const float ea = fmaf(-0.5f, ca, da);
        s1a = fmaf(ea, ca, s1a);
        s2a = fmaf(ea, fabsf(ca), s2a);
        const float db = reti - vb;
        const float cb = __builtin_amdgcn_fmed3f(db, -1.0f, 1.0f);
        const float eb = fmaf(-0.5f, cb, db);
        s1b = fmaf(eb, cb, s1b);
        s2b = fmaf(eb, fabsf(cb), s2b);
      };
#pragma unroll
      for (int i0 = 0; i0 < 48; i0 += 4) {
        const float4 rr = *reinterpret_cast<const float4*>(rp + i0);
        pair(rr.x); pair(rr.y); pair(rr.z); pair(rr.w);
      }
      {
        const float2 rr = *reinterpret_cast<const float2*>(rp + 48);
        pair(rr.x); pair(rr.y);
      }
      pacc[lr * PACC + jh] =
          fmaf(ta, s2a, 0.5f * s1a) + fmaf(tb, s2b, 0.5f * s1b);
    }
  }
  __syncthreads();

  // ---- per-row reduce: wave w handles rows 5w..5w+4 (25 partials each) ----
  const int w    = tid >> 6;
  const int lane = tid & 63;
#pragma unroll
  for (int k = 0; k < 5; ++k) {
    const int lr   = w * 5 + k;
    const int grow = r0 + lr;
    float x = (lane < 25) ? pacc[lr * PACC + lane] : 0.0f;
#pragma unroll
    for (int off = 16; off > 0; off >>= 1)
      x += __shfl_xor(x, off, 64);          // closes over lanes 0..31
    if (lane == 0 && grow < NROW)
      out[grow] = x * (1.0f / Q_DIM);
  }
}

// ---------------------------------------------------------------------------
extern "C" void kernel_launch(void* const* d_in, const int* in_sizes, int n_in,
                              void* d_out, int out_size, void* d_ws, size_t ws_size,
                              hipStream_t stream) {
  const float* reward       = (const float*)d_in[0];
  const int*   step_type    = (const int*)  d_in[1];
  const float* discount     = (const float*)d_in[2];
  const float* value        = (const float*)d_in[3];
  const float* target_value = (const float*)d_in[4];
  float* out = (float*)d_out;

  float* alpha  = (float*)d_ws;              // [512][128]
  float* beta   = alpha + B_DIM * 128;
  int*   anchor = (int*)(beta + B_DIM * 128);

  coeff_kernel<<<B_DIM, 128, 0, stream>>>(reward, step_type, discount,
                                          alpha, beta, anchor, out);

  loss_kernel<<<GRID_LOSS, 256, 0, stream>>>(value, target_value,
                                             alpha, beta, anchor, out);
}